// Round 1
// baseline (947.119 us; speedup 1.0000x reference)
//
#include <hip/hip_runtime.h>
#include <hip/hip_bf16.h>

typedef __bf16 bf16x8 __attribute__((ext_vector_type(8)));
typedef float floatx4 __attribute__((ext_vector_type(4)));

#define B_  16
#define P_  512
#define L_  12
#define H_  12
#define DH_ 64
#define M_  13
#define D_  768
#define K_  (L_*H_*DH_)   /* 9216 */
#define ROWS (B_*P_)      /* 8192 */

#define BM 32
#define BK 32
#define NSTEP (K_/BK)     /* 288 */
#define LDA 40            /* padded bf16 row stride for sA (80 B) */
#define SB_BYTES (D_*64)  /* 49152: 768 d-rows x 64 B (32 bf16 along k) */
#define WT_ELEMS (D_*BK)  /* 24576 bf16 per k-tile image */

typedef const __attribute__((address_space(1))) unsigned int* gas_u32p;
typedef __attribute__((address_space(3))) unsigned int*       las_u32p;

// ---------------------------------------------------------------------------
// Kernel 0: cb[b][d] = post_bias[d] + sum_m (1-mlp_mask)*mlp_constants
//                                   + sum_lh (1-attn_mask)*attn_constants
// ---------------------------------------------------------------------------
__global__ void cb_kernel(const float* __restrict__ mlp_mask,
                          const float* __restrict__ attn_mask,
                          const float* __restrict__ mlp_constants,
                          const float* __restrict__ attn_constants,
                          const float* __restrict__ post_bias,
                          float* __restrict__ cb) {
    int d = blockIdx.x * 128 + threadIdx.x;
    int b = blockIdx.y;
    float acc = post_bias[d];
    #pragma unroll
    for (int m = 0; m < M_; ++m)
        acc += (1.0f - mlp_mask[b*M_ + m]) * mlp_constants[m*D_ + d];
    for (int lh = 0; lh < L_*H_; ++lh)
        acc += (1.0f - attn_mask[b*L_*H_ + lh]) * attn_constants[lh*D_ + d];
    cb[b*D_ + d] = acc;
}

// ---------------------------------------------------------------------------
// Kernel 1: pre-pass. W_O fp32 [K=9216][D=768]  ->  WT bf16, per-k-tile
// 48 KB images laid out EXACTLY as the GEMM's sB wants them:
//   logical layout: [d=0..767][k_local=0..31] bf16 (64 B per d-row)
//   physical byte  p = jb ^ ((jb>>3)&48)   (involutive XOR swizzle: bank-
//   conflict-free ds_read_b128 of [d][quad*8..+8] fragments)
// GEMM staging then copies each 48 KB image with purely LINEAR
// global_load_lds dwordx4 (rule: linear dest + pre-swizzled source).
// ---------------------------------------------------------------------------
__global__ __launch_bounds__(256)
void wt_kernel(const float* __restrict__ W_O, __bf16* __restrict__ WT) {
    __shared__ __bf16 tile[D_*LDA];   // [d][k_local], padded: 768*40*2 = 61440 B
    const int tid = threadIdx.x;
    const int t   = blockIdx.x;       // k-tile 0..287
    const float* src = W_O + (size_t)t * BK * D_;
    #pragma unroll
    for (int it = 0; it < 24; ++it) {
        int f  = it*256 + tid;        // float4 index 0..6143
        int r  = f / 192;             // k row 0..31
        int c4 = f - r*192;           // float4 col 0..191
        float4 v = *(const float4*)(src + (size_t)r*D_ + c4*4);
        int d0 = c4*4;
        tile[(d0+0)*LDA + r] = (__bf16)v.x;
        tile[(d0+1)*LDA + r] = (__bf16)v.y;
        tile[(d0+2)*LDA + r] = (__bf16)v.z;
        tile[(d0+3)*LDA + r] = (__bf16)v.w;
    }
    __syncthreads();
    __bf16* dst = WT + (size_t)t * WT_ELEMS;
    #pragma unroll
    for (int it = 0; it < 12; ++it) {
        int p16 = (it*256 + tid) * 16;          // physical byte offset in image
        int jb  = p16 ^ ((p16 >> 3) & 48);      // logical byte offset
        int d   = jb >> 6;
        int seg = (jb >> 4) & 3;                // 8-bf16 run along k
        bf16x8 v = *(const bf16x8*)&tile[d*LDA + seg*8];
        *(bf16x8*)(dst + (p16 >> 1)) = v;       // coalesced dwordx4 store
    }
}

// ---------------------------------------------------------------------------
// Kernel 2: fused GEMM, full-width blocks.
// Grid = 256 blocks (BM=32 rows each) -> attn_cache read EXACTLY ONCE.
// 512 threads = 8 waves; wave w owns cols [w*96, w*96+96): acc 2x6 frags.
// Per K-step: B staged via 6 global_load_lds dwordx4/wave (linear, from
// pre-swizzled WT image); A (32x32 fp32) reg-prefetched 1 step ahead,
// mask folded during fp32->bf16 convert; single __syncthreads per step
// doubles as the vmcnt(0) handoff for the double-buffered LDS.
// ---------------------------------------------------------------------------
__global__ __launch_bounds__(512, 2)
void gemm_fused(const float* __restrict__ attn_cache,
                const __bf16* __restrict__ WT,
                const float* __restrict__ attn_mask,
                const float* __restrict__ mlp_mask,
                const float* __restrict__ mlp_cache,
                const float* __restrict__ cb,
                float* __restrict__ out) {
    __shared__ __bf16 sA[2][BM*LDA];                                  // 5120 B
    __shared__ __attribute__((aligned(16))) unsigned char sB[2][SB_BYTES]; // 98304 B
    __shared__ float sMlp[M_];

    const int tid   = threadIdx.x;
    const int rbase = blockIdx.x * BM;
    const int b     = rbase >> 9;          // 512 rows per batch -> uniform

    if (tid < M_) sMlp[tid] = mlp_mask[b*M_ + tid];

    const int wave = tid >> 6;
    const int lane = tid & 63;
    const int ln   = lane & 15;
    const int quad = lane >> 4;

    // A staging: thread -> (row 0..31, 2-float k segment)
    const int arow = tid >> 4;
    const int akk  = (tid & 15) * 2;
    const float* aSrc = attn_cache + (size_t)(rbase + arow) * K_ + akk;
    const float* amr  = attn_mask + b * (L_*H_);

    const unsigned char* wt = (const unsigned char*)WT;

    // B fragment physical offset: jb = d*64 + quad*16, phys = jb ^ ((jb>>3)&48)
    // (jb>>3)&48 depends only on ln -> hoisted; j*1024 strides are immediates.
    const int dbase = (wave*96 + ln)*64 + quad*16;
    const int bOff  = dbase ^ ((ln & 6) << 3);

    floatx4 acc[2][6];
    #pragma unroll
    for (int i = 0; i < 2; ++i)
        #pragma unroll
        for (int j = 0; j < 6; ++j)
            acc[i][j] = (floatx4){0.f, 0.f, 0.f, 0.f};

    // ---- prologue: B(0) -> sB[0]; A(0),A(1) -> regs; convert A(0) -> sA[0]
    #pragma unroll
    for (int c = 0; c < 6; ++c) {
        int boff = (wave*6 + c)*1024;
        __builtin_amdgcn_global_load_lds((gas_u32p)(const void*)(wt + boff + lane*16),
                                         (las_u32p)(void*)(&sB[0][boff]), 16, 0, 0);
    }
    float2 rX = *(const float2*)(aSrc);        // A(0)
    float2 rY = *(const float2*)(aSrc + BK);   // A(1)
    {
        float msk = amr[0];
        union { unsigned int u; __bf16 h[2]; } pk;
        pk.h[0] = (__bf16)(rX.x * msk);
        pk.h[1] = (__bf16)(rX.y * msk);
        *(unsigned int*)&sA[0][arow*LDA + akk] = pk.u;
    }
    __syncthreads();   // vmcnt(0): B(0) landed; lgkmcnt(0): sA[0] visible

    auto STEPF = [&](int T, float2& CUR, float2& NXT) {
        const int nb   = (T+1) & 1;
        const int cbuf = T & 1;
        // stage B(T+1) -> sB[nb]: 6 linear global_load_lds per wave
        if (T < NSTEP-1) {
            const unsigned char* wsrc = wt + (size_t)(T+1)*SB_BYTES;
            #pragma unroll
            for (int c = 0; c < 6; ++c) {
                int boff = (wave*6 + c)*1024;
                __builtin_amdgcn_global_load_lds((gas_u32p)(const void*)(wsrc + boff + lane*16),
                                                 (las_u32p)(void*)(&sB[nb][boff]), 16, 0, 0);
            }
        }
        // prefetch A(T+2) raw into regs (consumed next step)
        if (T < NSTEP-2) NXT = *(const float2*)(aSrc + (size_t)(T+2)*BK);
        // convert A(T+1) (mask folded) -> sA[nb]
        if (T < NSTEP-1) {
            float msk = amr[(T+1) >> 1];   // ((T+1)*32)>>6, uniform per tile
            union { unsigned int u; __bf16 h[2]; } pk;
            pk.h[0] = (__bf16)(CUR.x * msk);
            pk.h[1] = (__bf16)(CUR.y * msk);
            *(unsigned int*)&sA[nb][arow*LDA + akk] = pk.u;
        }
        // fragments + MFMA on buffers[cbuf]
        bf16x8 af[2], bfr[6];
        #pragma unroll
        for (int i = 0; i < 2; ++i)
            af[i] = *(const bf16x8*)&sA[cbuf][(i*16 + ln)*LDA + quad*8];
        #pragma unroll
        for (int j = 0; j < 6; ++j)
            bfr[j] = *(const bf16x8*)&sB[cbuf][bOff + j*1024];
        #pragma unroll
        for (int i = 0; i < 2; ++i)
            #pragma unroll
            for (int j = 0; j < 6; ++j)
                acc[i][j] = __builtin_amdgcn_mfma_f32_16x16x32_bf16(
                                af[i], bfr[j], acc[i][j], 0, 0, 0);
        __syncthreads();   // vmcnt(0)+lgkmcnt(0)+barrier: buffer handoff
    };

    for (int t2 = 0; t2 < NSTEP; t2 += 2) {
        STEPF(t2,   rY, rX);
        STEPF(t2+1, rX, rY);
    }

    // ---- epilogue: + mlp streams + cb, store fp32
    // C/D layout (verified m89/m91): col = lane&15, row = quad*4 + reg
    #pragma unroll
    for (int j = 0; j < 6; ++j) {
        const int d   = wave*96 + j*16 + ln;
        const float cbv = cb[b*D_ + d];
        #pragma unroll
        for (int i = 0; i < 2; ++i) {
            const int rloc = i*16 + quad*4;
            #pragma unroll
            for (int v = 0; v < 4; ++v) {
                const size_t r = (size_t)rbase + rloc + v;
                float s = acc[i][j][v] + cbv;
                const float* mc = mlp_cache + r * (size_t)(M_*D_) + d;
                #pragma unroll
                for (int m = 0; m < M_; ++m)
                    s += sMlp[m] * mc[(size_t)m * D_];
                out[r * D_ + d] = s;
            }
        }
    }
}

// ---------------------------------------------------------------------------
// Workspace layout: [0, 48K): cb   [64K, 64K+13.5M): WT (pre-converted W_O)
// Requires ws_size >= 14,221,312 B.
// ---------------------------------------------------------------------------
extern "C" void kernel_launch(void* const* d_in, const int* in_sizes, int n_in,
                              void* d_out, int out_size, void* d_ws, size_t ws_size,
                              hipStream_t stream) {
    const float* mlp_cache      = (const float*)d_in[0];
    const float* attn_cache     = (const float*)d_in[1];
    const float* mlp_mask       = (const float*)d_in[2];
    const float* attn_mask      = (const float*)d_in[3];
    const float* mlp_constants  = (const float*)d_in[4];
    const float* attn_constants = (const float*)d_in[5];
    const float* W_O            = (const float*)d_in[6];
    const float* post_bias      = (const float*)d_in[7];
    float* out = (float*)d_out;

    float*  cbw = (float*)d_ws;
    __bf16* wtw = (__bf16*)((char*)d_ws + 65536);

    cb_kernel<<<dim3(D_/128, B_), 128, 0, stream>>>(
        mlp_mask, attn_mask, mlp_constants, attn_constants, post_bias, cbw);

    wt_kernel<<<dim3(NSTEP), 256, 0, stream>>>(W_O, wtw);

    gemm_fused<<<dim3(ROWS/BM), 512, 0, stream>>>(
        attn_cache, wtw, attn_mask, mlp_mask, mlp_cache, cbw, out);
}